// Round 12
// baseline (167.042 us; speedup 1.0000x reference)
//
#include <hip/hip_runtime.h>

#define NN 50000
#define NE 1600000
#define DF 128
#define NB 1250     // buckets
#define BSZ 40      // dst nodes per bucket (NB*BSZ == NN)
#define CAP 1664    // per-bucket capacity; load 1280 +/- 36 -> +10.7 sigma
#define NWGP 512    // partition workgroups
#define CHKP 3125   // edges per partition wg (NWGP*CHKP == NE)
#define NBN 12500   // norm blocks (4 waves each -> NN waves)

static __device__ __forceinline__ float bflo(unsigned int u) {
    unsigned int v = u << 16; float f; __builtin_memcpy(&f, &v, 4); return f;
}
static __device__ __forceinline__ float bfhi(unsigned int u) {
    unsigned int v = u & 0xFFFF0000u; float f; __builtin_memcpy(&f, &v, 4); return f;
}
static __device__ __forceinline__ unsigned int f2bf(float f) {   // RNE, low 16 bits
    unsigned int u; __builtin_memcpy(&u, &f, 4);
    u += 0x7FFFu + ((u >> 16) & 1u);
    return u >> 16;
}

// Block-wide exclusive scan over 256 values (one per thread). 2 barriers.
static __device__ __forceinline__ int block_excl_scan(int v, int t, int* wsum4) {
    int lane = t & 63, wv = t >> 6;
    int s = v;
    #pragma unroll
    for (int off = 1; off < 64; off <<= 1) {
        int u = __shfl_up(s, off);
        if (lane >= off) s += u;
    }
    if (lane == 63) wsum4[wv] = s;
    __syncthreads();
    int add = 0;
    #pragma unroll
    for (int w = 0; w < 4; ++w) add += (w < wv) ? wsum4[w] : 0;
    __syncthreads();
    return s + add - v;      // exclusive
}

// ---------------------------------------------------------------------------
// K1 (fused; partition blocks first so the heavy phase starts immediately):
//  blocks [0,NWGP):  wg-local counting sort of 3125 edges by bucket in LDS;
//                    sorted records streamed out COALESCED into the wg's
//                    private pairs slab; descriptor row descG[wg][b] =
//                    (runoff<<16 | runlen), coalesced. No global atomics.
//  blocks [NWGP,..): one wave per node: xn_bf = bf16(x*rsqrt(max(ss,eps^2))),
//                    norm = ||x||. Softmax later shifts by the constant |beta|
//                    (exact by shift-invariance; the self-loop keeps every
//                    denominator >= exp(-2|beta|) > 0).
// ---------------------------------------------------------------------------
__global__ __launch_bounds__(256)
void k_norm_part(const float* __restrict__ x,
                 const int* __restrict__ ei,
                 unsigned int* __restrict__ xn_bf,
                 float* __restrict__ norm,
                 unsigned int* __restrict__ descG,
                 unsigned int* __restrict__ pairs) {
    __shared__ int wsum4[4];
    __shared__ int cntL[NB];
    __shared__ int offL[NB];
    __shared__ unsigned int stg[CHKP];
    if (blockIdx.x >= NWGP) {
        int node = ((blockIdx.x - NWGP) * 256 + threadIdx.x) >> 6;
        int lane = threadIdx.x & 63;
        float2 v = ((const float2*)(x + (size_t)node * DF))[lane];
        float ss = v.x * v.x + v.y * v.y;
        #pragma unroll
        for (int m = 1; m < 64; m <<= 1) ss += __shfl_xor(ss, m);
        float rinv = rsqrtf(fmaxf(ss, 1e-24f));
        xn_bf[(size_t)node * 64 + lane] = (f2bf(v.y * rinv) << 16) | f2bf(v.x * rinv);
        if (lane == 0) norm[node] = ss * rinv;       // == ||x||, smooth at 0
        return;
    }
    int wg = blockIdx.x, t = threadIdx.x;
    const int* srcp = ei + wg * CHKP;
    const int* dstp = ei + NE + wg * CHKP;
    for (int i = t; i < NB; i += 256) cntL[i] = 0;
    __syncthreads();
    for (int i = t; i < CHKP; i += 256) atomicAdd(&cntL[dstp[i] / BSZ], 1);
    __syncthreads();
    {   // exclusive scan of cntL[0..NB): 5 consecutive values per thread
        int base = t * 5;
        int loc[5];
        int s = 0;
        #pragma unroll
        for (int q = 0; q < 5; ++q) {
            int idx = base + q;
            int v = (idx < NB) ? cntL[idx] : 0;
            loc[q] = s;
            s += v;
        }
        int ex = block_excl_scan(s, t, wsum4);
        #pragma unroll
        for (int q = 0; q < 5; ++q) {
            int idx = base + q;
            if (idx < NB) offL[idx] = ex + loc[q];
        }
    }
    __syncthreads();
    // packed descriptor row, coalesced (off<=3125, cnt<=3125 both fit 16 bits)
    for (int i = t; i < NB; i += 256)
        descG[(size_t)wg * NB + i] = ((unsigned int)offL[i] << 16) | (unsigned int)cntL[i];
    __syncthreads();                 // all offL reads done before cursor bumps
    for (int i = t; i < CHKP; i += 256) {
        int src = srcp[i];
        int dst = dstp[i];
        int b = dst / BSZ;
        int pos = atomicAdd(&offL[b], 1);
        stg[pos] = ((unsigned int)(dst - b * BSZ) << 16) | (unsigned int)src;
    }
    __syncthreads();
    unsigned int* chunk = pairs + (size_t)wg * CHKP;
    for (int i = t; i < CHKP; i += 256) chunk[i] = stg[i];
}

// ---------------------------------------------------------------------------
// K2 (build): one block per bucket. Merge the 512 runs with 16-lane
// cooperative copies (group per run, lanes split elements — no divergent
// serial loops), LDS hist over 40 local dst, single-wave scan, LDS fill of
// colL packing bf16(norm[src]); stream colL out coalesced into the bucket's
// CAP-strided colG window; per-node [begin,end) as one int2.
// ---------------------------------------------------------------------------
__global__ __launch_bounds__(256)
void k_build(const float* __restrict__ norm,
             const unsigned int* __restrict__ descG,
             const unsigned int* __restrict__ pairs,
             unsigned int* __restrict__ colG,
             int2* __restrict__ rp2) {
    __shared__ int wsum4[4];
    __shared__ int lenS[NWGP], offS[NWGP], rbase[NWGP];
    __shared__ unsigned int rawL[CAP];
    __shared__ unsigned int colL[CAP];
    __shared__ int hist[BSZ];
    __shared__ int rp[BSZ + 1];
    __shared__ int tot0, stotal;
    int b = blockIdx.x, t = threadIdx.x;

    unsigned int d0 = descG[(size_t)t * NB + b];
    unsigned int d1 = descG[(size_t)(t + 256) * NB + b];
    int len0 = (int)(d0 & 0xFFFFu), off0 = (int)(d0 >> 16);
    int len1 = (int)(d1 & 0xFFFFu), off1 = (int)(d1 >> 16);
    int rb0 = block_excl_scan(len0, t, wsum4);
    if (t == 255) tot0 = rb0 + len0;
    int ex1 = block_excl_scan(len1, t, wsum4);   // internal barrier publishes tot0
    int rb1 = tot0 + ex1;
    if (t == 255) stotal = rb1 + len1;
    lenS[t] = len0;        offS[t] = off0;        rbase[t] = rb0;
    lenS[t + 256] = len1;  offS[t + 256] = off1;  rbase[t + 256] = rb1;
    if (t < BSZ) hist[t] = 0;
    __syncthreads();
    int cnt = stotal;
    if (cnt > CAP) cnt = CAP;        // never fires (memory safety)

    // cooperative run copy: 16 groups x 16 lanes; 32 run-iterations total
    int g16 = t >> 4, l16 = t & 15;
    for (int r = g16; r < NWGP; r += 16) {
        int len = lenS[r];
        int rb = rbase[r];
        const unsigned int* sp = pairs + (size_t)r * CHKP + offS[r];
        for (int q = l16; q < len; q += 16) {
            int pos = rb + q;
            if (pos < CAP) rawL[pos] = sp[q];
        }
    }
    __syncthreads();
    for (int i = t; i < cnt; i += 256) atomicAdd(&hist[rawL[i] >> 16], 1);
    __syncthreads();
    if (t < 64) {                    // single-wave scan (BSZ=40 < 64)
        int v = (t < BSZ) ? hist[t] : 0;
        int s = v;
        #pragma unroll
        for (int off = 1; off < 64; off <<= 1) {
            int u = __shfl_up(s, off);
            if (t >= off) s += u;
        }
        if (t < BSZ) { rp[t + 1] = s; hist[t] = s - v; }   // cursor = exclusive
        if (t == 0) rp[0] = 0;
    }
    __syncthreads();
    for (int i = t; i < cnt; i += 256) {
        unsigned int p = rawL[i];
        unsigned int src = p & 0xFFFFu;
        int pos = atomicAdd(&hist[p >> 16], 1);
        colL[pos] = (f2bf(norm[src]) << 16) | src;
    }
    __syncthreads();
    int base = b * CAP;
    for (int i = t; i < cnt; i += 256) colG[base + i] = colL[i];
    if (t < BSZ) {
        int2 v; v.x = base + rp[t]; v.y = base + rp[t + 1];
        rp2[b * BSZ + t] = v;
    }
}

// ---------------------------------------------------------------------------
// K3 (gather): one wave per dst node (12500 blocks -> full occupancy), 4
// groups x 16 lanes, 2-edge software pipeline; per edge one packed 4B
// (norm|src) load + one 16B bf16 row load. Measured at ~52.6us in R8.
// ---------------------------------------------------------------------------
__global__ __launch_bounds__(256)
void k_gather(const unsigned int* __restrict__ xn_bf,
              const float* __restrict__ norm,
              const int2* __restrict__ rp2,
              const unsigned int* __restrict__ colG,
              const float* __restrict__ beta_p,
              float* __restrict__ out) {
    int node = (blockIdx.x * blockDim.x + threadIdx.x) >> 6;
    int lane = threadIdx.x & 63;
    if (node >= NN) return;
    int j = lane & 15;
    int g = lane >> 4;
    float beta = beta_p[0];
    float c = -fabsf(beta);

    uint4 du = ((const uint4*)(xn_bf + (size_t)node * 64))[j];
    float xd[8];
    #pragma unroll
    for (int q = 0; q < 4; ++q) {
        unsigned int u = (&du.x)[q];
        xd[2 * q]     = bflo(u);
        xd[2 * q + 1] = bfhi(u);
    }

    float acc[8] = {0.f, 0.f, 0.f, 0.f, 0.f, 0.f, 0.f, 0.f};
    float ssum = 0.f;
    int2 rr = rp2[node];
    int b0 = rr.x, b1 = rr.y;

    int k = b0 + g;
    int kA = (k     < b1) ? k     : 0;
    int kB = (k + 4 < b1) ? k + 4 : 0;
    unsigned int pA = colG[kA];
    unsigned int pB = colG[kB];
    uint4 rA = ((const uint4*)(xn_bf + (size_t)(pA & 0xFFFFu) * 64))[j];
    uint4 rB = ((const uint4*)(xn_bf + (size_t)(pB & 0xFFFFu) * 64))[j];

    for (; k < b1; k += 8) {
        int kC = (k +  8 < b1) ? k +  8 : 0;
        int kD = (k + 12 < b1) ? k + 12 : 0;
        unsigned int pC = colG[kC];
        unsigned int pD = colG[kD];
        uint4 rC = ((const uint4*)(xn_bf + (size_t)(pC & 0xFFFFu) * 64))[j];
        uint4 rD = ((const uint4*)(xn_bf + (size_t)(pD & 0xFFFFu) * 64))[j];
        {   // edge A (always valid: k < b1)
            float xs[8];
            #pragma unroll
            for (int q = 0; q < 4; ++q) {
                unsigned int u = (&rA.x)[q];
                xs[2 * q]     = bflo(u);
                xs[2 * q + 1] = bfhi(u);
            }
            float dot = 0.f;
            #pragma unroll
            for (int q = 0; q < 8; ++q) dot = fmaf(xd[q], xs[q], dot);
            dot += __shfl_xor(dot, 1);
            dot += __shfl_xor(dot, 2);
            dot += __shfl_xor(dot, 4);
            dot += __shfl_xor(dot, 8);
            float e = __expf(fmaf(beta, dot, c));
            ssum += e;
            float wgt = e * bfhi(pA);
            #pragma unroll
            for (int q = 0; q < 8; ++q) acc[q] = fmaf(wgt, xs[q], acc[q]);
        }
        {   // edge B (valid iff k+4 < b1)
            float xs[8];
            #pragma unroll
            for (int q = 0; q < 4; ++q) {
                unsigned int u = (&rB.x)[q];
                xs[2 * q]     = bflo(u);
                xs[2 * q + 1] = bfhi(u);
            }
            float dot = 0.f;
            #pragma unroll
            for (int q = 0; q < 8; ++q) dot = fmaf(xd[q], xs[q], dot);
            dot += __shfl_xor(dot, 1);
            dot += __shfl_xor(dot, 2);
            dot += __shfl_xor(dot, 4);
            dot += __shfl_xor(dot, 8);
            float e = __expf(fmaf(beta, dot, c));
            e = (k + 4 < b1) ? e : 0.f;
            ssum += e;
            float wgt = e * bfhi(pB);
            #pragma unroll
            for (int q = 0; q < 8; ++q) acc[q] = fmaf(wgt, xs[q], acc[q]);
        }
        pA = pC; pB = pD; rA = rC; rB = rD;
    }

    ssum += __shfl_xor(ssum, 16);
    ssum += __shfl_xor(ssum, 32);
    #pragma unroll
    for (int q = 0; q < 8; ++q) {
        acc[q] += __shfl_xor(acc[q], 16);
        acc[q] += __shfl_xor(acc[q], 32);
    }
    float e_self = __expf(beta + c);          // self-loop, cos = 1
    ssum += e_self;
    float wsl = e_self * norm[node];
    #pragma unroll
    for (int q = 0; q < 8; ++q) acc[q] = fmaf(wsl, xd[q], acc[q]);

    if (g == 0) {
        float inv = 1.0f / ssum;
        float4 o0, o1;
        o0.x = fmaxf(0.f, acc[0] * inv); o0.y = fmaxf(0.f, acc[1] * inv);
        o0.z = fmaxf(0.f, acc[2] * inv); o0.w = fmaxf(0.f, acc[3] * inv);
        o1.x = fmaxf(0.f, acc[4] * inv); o1.y = fmaxf(0.f, acc[5] * inv);
        o1.z = fmaxf(0.f, acc[6] * inv); o1.w = fmaxf(0.f, acc[7] * inv);
        float4* op = (float4*)(out + (size_t)node * DF + 8 * j);
        op[0] = o0;
        op[1] = o1;
    }
}

extern "C" void kernel_launch(void* const* d_in, const int* in_sizes, int n_in,
                              void* d_out, int out_size, void* d_ws, size_t ws_size,
                              hipStream_t stream) {
    const float* x    = (const float*)d_in[0];   // fp32 [NN*DF]
    const float* beta = (const float*)d_in[1];   // fp32 [1]
    const int*   ei   = (const int*)d_in[2];     // int32 [2*NE]
    float*       out  = (float*)d_out;           // fp32 [NN*DF]

    // workspace layout (bytes), total ~30.7 MiB:
    char* ws = (char*)d_ws;
    unsigned int* xn_bf = (unsigned int*)ws;                  // NN*64*4 = 12,800,000
    float* norm = (float*)(ws + 12800000);                    // NN*4    =    200,000
    unsigned int* descG = (unsigned int*)(ws + 13000000);     // NWGP*NB*4 = 2,560,000
    unsigned int* pairs = (unsigned int*)(ws + 15560000);     // NE*4 = 6,400,000
    unsigned int* colG  = (unsigned int*)(ws + 21960000);     // NB*CAP*4 = 8,320,000
    int2* rp2 = (int2*)(ws + 30280000);                       // NN*8 = 400,000

    k_norm_part<<<NWGP + NBN, 256, 0, stream>>>(x, ei, xn_bf, norm, descG, pairs);
    k_build    <<<NB,         256, 0, stream>>>(norm, descG, pairs, colG, rp2);
    k_gather   <<<(NN * 64 + 255) / 256, 256, 0, stream>>>(xn_bf, norm, rp2, colG, beta, out);
}

// Round 13
// 162.128 us; speedup vs baseline: 1.0303x; 1.0303x over previous
//
#include <hip/hip_runtime.h>

#define NN 50000
#define NE 1600000
#define DF 128
#define NB 1250     // buckets
#define BSZ 40      // dst nodes per bucket (NB*BSZ == NN)
#define CAP 1664    // per-bucket capacity; load 1280 +/- 36 -> +10.7 sigma
#define NWGP 512    // partition workgroups
#define CHKP 3125   // edges per partition wg (NWGP*CHKP == NE)
#define NBF 3125    // norm blocks: 16 rows each (512 thr, float4) -> NN rows

static __device__ __forceinline__ float bflo(unsigned int u) {
    unsigned int v = u << 16; float f; __builtin_memcpy(&f, &v, 4); return f;
}
static __device__ __forceinline__ float bfhi(unsigned int u) {
    unsigned int v = u & 0xFFFF0000u; float f; __builtin_memcpy(&f, &v, 4); return f;
}
static __device__ __forceinline__ unsigned int f2bf(float f) {   // RNE, low 16 bits
    unsigned int u; __builtin_memcpy(&u, &f, 4);
    u += 0x7FFFu + ((u >> 16) & 1u);
    return u >> 16;
}

// Block-wide exclusive scan, 512 threads (8 waves). 2 barriers.
static __device__ __forceinline__ int block_excl_scan512(int v, int t, int* wsum8) {
    int lane = t & 63, wv = t >> 6;
    int s = v;
    #pragma unroll
    for (int off = 1; off < 64; off <<= 1) {
        int u = __shfl_up(s, off);
        if (lane >= off) s += u;
    }
    if (lane == 63) wsum8[wv] = s;
    __syncthreads();
    int add = 0;
    #pragma unroll
    for (int w = 0; w < 8; ++w) add += (w < wv) ? wsum8[w] : 0;
    __syncthreads();
    return s + add - v;      // exclusive
}

// Block-wide exclusive scan, 256 threads (4 waves). 2 barriers.
static __device__ __forceinline__ int block_excl_scan256(int v, int t, int* wsum4) {
    int lane = t & 63, wv = t >> 6;
    int s = v;
    #pragma unroll
    for (int off = 1; off < 64; off <<= 1) {
        int u = __shfl_up(s, off);
        if (lane >= off) s += u;
    }
    if (lane == 63) wsum4[wv] = s;
    __syncthreads();
    int add = 0;
    #pragma unroll
    for (int w = 0; w < 4; ++w) add += (w < wv) ? wsum4[w] : 0;
    __syncthreads();
    return s + add - v;      // exclusive
}

// ---------------------------------------------------------------------------
// K1 (512-thread blocks; partition blocks first so the tail phase gets all
// the latency-hiding it can):
//  blocks [0,NWGP):  wg-local counting sort of 3125 edges by bucket in LDS
//                    (8 waves/block, unroll-4 loops -> 4+ loads in flight);
//                    sorted records streamed out COALESCED into the wg's
//                    private pairs slab; packed descriptor row
//                    descG[wg][b] = (runoff<<16 | runlen). No global atomics.
//  blocks [NWGP,..): norm, float4: 32 lanes/row, 2 rows/wave, 16 rows/block:
//                    xn_bf = bf16(x*rsqrt(max(ss,eps^2))), norm = ||x||.
//                    Softmax later shifts by the constant |beta| (exact by
//                    shift-invariance; the self-loop keeps every denominator
//                    >= exp(-2|beta|) > 0).
// ---------------------------------------------------------------------------
__global__ __launch_bounds__(512)
void k_norm_part(const float* __restrict__ x,
                 const int* __restrict__ ei,
                 unsigned int* __restrict__ xn_bf,
                 float* __restrict__ norm,
                 unsigned int* __restrict__ descG,
                 unsigned int* __restrict__ pairs) {
    __shared__ int wsum8[8];
    __shared__ int cntL[NB];
    __shared__ int offL[NB];
    __shared__ unsigned int stg[CHKP];
    int t = threadIdx.x;
    if (blockIdx.x >= NWGP) {
        int nbid = blockIdx.x - NWGP;
        int l32 = t & 31;
        int node = nbid * 16 + ((t >> 6) << 1) + ((t & 63) >> 5);
        float4 v = ((const float4*)(x + (size_t)node * DF))[l32];
        float ss = v.x * v.x + v.y * v.y + v.z * v.z + v.w * v.w;
        #pragma unroll
        for (int m = 1; m < 32; m <<= 1) ss += __shfl_xor(ss, m);  // 32-lane half
        float rinv = rsqrtf(fmaxf(ss, 1e-24f));
        uint2 p;
        p.x = (f2bf(v.y * rinv) << 16) | f2bf(v.x * rinv);
        p.y = (f2bf(v.w * rinv) << 16) | f2bf(v.z * rinv);
        ((uint2*)(xn_bf + (size_t)node * 64))[l32] = p;
        if (l32 == 0) norm[node] = ss * rinv;        // == ||x||, smooth at 0
        return;
    }
    int wg = blockIdx.x;
    const int* srcp = ei + wg * CHKP;
    const int* dstp = ei + NE + wg * CHKP;
    for (int i = t; i < NB; i += 512) cntL[i] = 0;
    __syncthreads();
    #pragma unroll 4
    for (int i = t; i < CHKP; i += 512) atomicAdd(&cntL[dstp[i] / BSZ], 1);
    __syncthreads();
    {   // exclusive scan of cntL[0..NB): 3 consecutive values per thread
        int base = t * 3;
        int loc[3];
        int s = 0;
        #pragma unroll
        for (int q = 0; q < 3; ++q) {
            int idx = base + q;
            int v = (idx < NB) ? cntL[idx] : 0;
            loc[q] = s;
            s += v;
        }
        int ex = block_excl_scan512(s, t, wsum8);
        #pragma unroll
        for (int q = 0; q < 3; ++q) {
            int idx = base + q;
            if (idx < NB) offL[idx] = ex + loc[q];
        }
    }
    __syncthreads();
    // packed descriptor row, coalesced (off,cnt <= 3125 both fit 16 bits)
    for (int i = t; i < NB; i += 512)
        descG[(size_t)wg * NB + i] = ((unsigned int)offL[i] << 16) | (unsigned int)cntL[i];
    __syncthreads();                 // all offL reads done before cursor bumps
    #pragma unroll 2
    for (int i = t; i < CHKP; i += 512) {
        int src = srcp[i];
        int dst = dstp[i];
        int b = dst / BSZ;
        int pos = atomicAdd(&offL[b], 1);
        stg[pos] = ((unsigned int)(dst - b * BSZ) << 16) | (unsigned int)src;
    }
    __syncthreads();
    unsigned int* chunk = pairs + (size_t)wg * CHKP;
    #pragma unroll 4
    for (int i = t; i < CHKP; i += 512) chunk[i] = stg[i];
}

// ---------------------------------------------------------------------------
// K2 (fused build + gather): one block (256 thr) per bucket; 1250 blocks all
// co-resident (LDS ~20 KB -> 8 blocks/CU).
//  Merge: cooperative 16-lane run copies (group per run) of the 512 runs into
//  rawL. Build: LDS hist over 40 local dst, single-wave scan -> rp, LDS fill
//  of colL packing bf16(norm[src]) in the high bits. colL/rp never touch
//  global. Gather: wave w handles local nodes w, w+4,...; 4 groups x 16
//  lanes, 2-edge software pipeline; col reads are LDS.
// ---------------------------------------------------------------------------
__global__ __launch_bounds__(256)
void k_build_gather(const unsigned int* __restrict__ xn_bf,
                    const float* __restrict__ norm,
                    const unsigned int* __restrict__ descG,
                    const unsigned int* __restrict__ pairs,
                    const float* __restrict__ beta_p,
                    float* __restrict__ out) {
    __shared__ int wsum4[4];
    __shared__ int lenS[NWGP], offS[NWGP], rbase[NWGP];
    __shared__ unsigned int rawL[CAP];
    __shared__ unsigned int colL[CAP];
    __shared__ int hist[BSZ];
    __shared__ int rp[BSZ + 1];
    __shared__ int tot0, stotal;
    int b = blockIdx.x, t = threadIdx.x;

    unsigned int d0 = descG[(size_t)t * NB + b];
    unsigned int d1 = descG[(size_t)(t + 256) * NB + b];
    int len0 = (int)(d0 & 0xFFFFu), off0 = (int)(d0 >> 16);
    int len1 = (int)(d1 & 0xFFFFu), off1 = (int)(d1 >> 16);
    int rb0 = block_excl_scan256(len0, t, wsum4);
    if (t == 255) tot0 = rb0 + len0;
    int ex1 = block_excl_scan256(len1, t, wsum4);   // internal barrier publishes tot0
    int rb1 = tot0 + ex1;
    if (t == 255) stotal = rb1 + len1;
    lenS[t] = len0;        offS[t] = off0;        rbase[t] = rb0;
    lenS[t + 256] = len1;  offS[t + 256] = off1;  rbase[t + 256] = rb1;
    if (t < BSZ) hist[t] = 0;
    __syncthreads();
    int cnt = stotal;
    if (cnt > CAP) cnt = CAP;        // never fires (memory safety)

    // cooperative run copy: 16 groups x 16 lanes; 32 run-iterations total
    int g16 = t >> 4, l16 = t & 15;
    for (int r = g16; r < NWGP; r += 16) {
        int len = lenS[r];
        int rb = rbase[r];
        const unsigned int* sp = pairs + (size_t)r * CHKP + offS[r];
        for (int q = l16; q < len; q += 16) {
            int pos = rb + q;
            if (pos < CAP) rawL[pos] = sp[q];
        }
    }
    __syncthreads();
    for (int i = t; i < cnt; i += 256) atomicAdd(&hist[rawL[i] >> 16], 1);
    __syncthreads();
    if (t < 64) {                    // single-wave scan (BSZ=40 < 64)
        int v = (t < BSZ) ? hist[t] : 0;
        int s = v;
        #pragma unroll
        for (int off = 1; off < 64; off <<= 1) {
            int u = __shfl_up(s, off);
            if (t >= off) s += u;
        }
        if (t < BSZ) { rp[t + 1] = s; hist[t] = s - v; }   // cursor = exclusive
        if (t == 0) rp[0] = 0;
    }
    __syncthreads();
    for (int i = t; i < cnt; i += 256) {
        unsigned int p = rawL[i];
        unsigned int src = p & 0xFFFFu;
        int pos = atomicAdd(&hist[p >> 16], 1);
        colL[pos] = (f2bf(norm[src]) << 16) | src;
    }
    __syncthreads();

    // ---- gather (col/rp from LDS) ----
    int lane = t & 63;
    int w = t >> 6;
    int j = lane & 15;
    int g = lane >> 4;
    float beta = beta_p[0];
    float c = -fabsf(beta);
    for (int ln = w; ln < BSZ; ln += 4) {
        int node = b * BSZ + ln;
        uint4 du = ((const uint4*)(xn_bf + (size_t)node * 64))[j];
        float xd[8];
        #pragma unroll
        for (int q = 0; q < 4; ++q) {
            unsigned int u = (&du.x)[q];
            xd[2 * q]     = bflo(u);
            xd[2 * q + 1] = bfhi(u);
        }
        float acc[8] = {0.f, 0.f, 0.f, 0.f, 0.f, 0.f, 0.f, 0.f};
        float ssum = 0.f;
        int b0 = rp[ln], b1 = rp[ln + 1];

        int k = b0 + g;
        int kA = (k     < b1) ? k     : 0;
        int kB = (k + 4 < b1) ? k + 4 : 0;
        unsigned int pA = colL[kA];
        unsigned int pB = colL[kB];
        uint4 rA = ((const uint4*)(xn_bf + (size_t)(pA & 0xFFFFu) * 64))[j];
        uint4 rB = ((const uint4*)(xn_bf + (size_t)(pB & 0xFFFFu) * 64))[j];

        for (; k < b1; k += 8) {
            int kC = (k +  8 < b1) ? k +  8 : 0;
            int kD = (k + 12 < b1) ? k + 12 : 0;
            unsigned int pC = colL[kC];
            unsigned int pD = colL[kD];
            uint4 rC = ((const uint4*)(xn_bf + (size_t)(pC & 0xFFFFu) * 64))[j];
            uint4 rD = ((const uint4*)(xn_bf + (size_t)(pD & 0xFFFFu) * 64))[j];
            {   // edge A (always valid: k < b1)
                float xs[8];
                #pragma unroll
                for (int q = 0; q < 4; ++q) {
                    unsigned int u = (&rA.x)[q];
                    xs[2 * q]     = bflo(u);
                    xs[2 * q + 1] = bfhi(u);
                }
                float dot = 0.f;
                #pragma unroll
                for (int q = 0; q < 8; ++q) dot = fmaf(xd[q], xs[q], dot);
                dot += __shfl_xor(dot, 1);
                dot += __shfl_xor(dot, 2);
                dot += __shfl_xor(dot, 4);
                dot += __shfl_xor(dot, 8);
                float e = __expf(fmaf(beta, dot, c));
                ssum += e;
                float wgt = e * bfhi(pA);
                #pragma unroll
                for (int q = 0; q < 8; ++q) acc[q] = fmaf(wgt, xs[q], acc[q]);
            }
            {   // edge B (valid iff k+4 < b1)
                float xs[8];
                #pragma unroll
                for (int q = 0; q < 4; ++q) {
                    unsigned int u = (&rB.x)[q];
                    xs[2 * q]     = bflo(u);
                    xs[2 * q + 1] = bfhi(u);
                }
                float dot = 0.f;
                #pragma unroll
                for (int q = 0; q < 8; ++q) dot = fmaf(xd[q], xs[q], dot);
                dot += __shfl_xor(dot, 1);
                dot += __shfl_xor(dot, 2);
                dot += __shfl_xor(dot, 4);
                dot += __shfl_xor(dot, 8);
                float e = __expf(fmaf(beta, dot, c));
                e = (k + 4 < b1) ? e : 0.f;
                ssum += e;
                float wgt = e * bfhi(pB);
                #pragma unroll
                for (int q = 0; q < 8; ++q) acc[q] = fmaf(wgt, xs[q], acc[q]);
            }
            pA = pC; pB = pD; rA = rC; rB = rD;
        }

        ssum += __shfl_xor(ssum, 16);
        ssum += __shfl_xor(ssum, 32);
        #pragma unroll
        for (int q = 0; q < 8; ++q) {
            acc[q] += __shfl_xor(acc[q], 16);
            acc[q] += __shfl_xor(acc[q], 32);
        }
        float e_self = __expf(beta + c);          // self-loop, cos = 1
        ssum += e_self;
        float wsl = e_self * norm[node];
        #pragma unroll
        for (int q = 0; q < 8; ++q) acc[q] = fmaf(wsl, xd[q], acc[q]);

        if (g == 0) {
            float inv = 1.0f / ssum;
            float4 o0, o1;
            o0.x = fmaxf(0.f, acc[0] * inv); o0.y = fmaxf(0.f, acc[1] * inv);
            o0.z = fmaxf(0.f, acc[2] * inv); o0.w = fmaxf(0.f, acc[3] * inv);
            o1.x = fmaxf(0.f, acc[4] * inv); o1.y = fmaxf(0.f, acc[5] * inv);
            o1.z = fmaxf(0.f, acc[6] * inv); o1.w = fmaxf(0.f, acc[7] * inv);
            float4* op = (float4*)(out + (size_t)node * DF + 8 * j);
            op[0] = o0;
            op[1] = o1;
        }
    }
}

extern "C" void kernel_launch(void* const* d_in, const int* in_sizes, int n_in,
                              void* d_out, int out_size, void* d_ws, size_t ws_size,
                              hipStream_t stream) {
    const float* x    = (const float*)d_in[0];   // fp32 [NN*DF]
    const float* beta = (const float*)d_in[1];   // fp32 [1]
    const int*   ei   = (const int*)d_in[2];     // int32 [2*NE]
    float*       out  = (float*)d_out;           // fp32 [NN*DF]

    // workspace layout (bytes), total ~21.0 MiB:
    char* ws = (char*)d_ws;
    unsigned int* xn_bf = (unsigned int*)ws;                  // NN*64*4 = 12,800,000
    float* norm = (float*)(ws + 12800000);                    // NN*4    =    200,000
    unsigned int* descG = (unsigned int*)(ws + 13000000);     // NWGP*NB*4 = 2,560,000
    unsigned int* pairs = (unsigned int*)(ws + 15560000);     // NE*4 = 6,400,000

    k_norm_part  <<<NWGP + NBF, 512, 0, stream>>>(x, ei, xn_bf, norm, descG, pairs);
    k_build_gather<<<NB,        256, 0, stream>>>(xn_bf, norm, descG, pairs, beta, out);
}

// Round 14
// 162.075 us; speedup vs baseline: 1.0306x; 1.0003x over previous
//
#include <hip/hip_runtime.h>

#define NN 50000
#define NE 1600000
#define DF 128
#define NB 1250     // buckets
#define BSZ 40      // dst nodes per bucket (NB*BSZ == NN)
#define CAP 1664    // per-bucket capacity; load 1280 +/- 36 -> +10.7 sigma
#define NWGA 1024   // partition workgroups (4 x 512thr per CU -> 100% occupancy)
#define CHKA 1563   // edges per partition wg (1024*1563 >= NE; last wg short)
#define NBF 3125    // norm blocks: 16 rows each (512 thr, float4) -> NN rows

static __device__ __forceinline__ float bflo(unsigned int u) {
    unsigned int v = u << 16; float f; __builtin_memcpy(&f, &v, 4); return f;
}
static __device__ __forceinline__ float bfhi(unsigned int u) {
    unsigned int v = u & 0xFFFF0000u; float f; __builtin_memcpy(&f, &v, 4); return f;
}
static __device__ __forceinline__ unsigned int f2bf(float f) {   // RNE, low 16 bits
    unsigned int u; __builtin_memcpy(&u, &f, 4);
    u += 0x7FFFu + ((u >> 16) & 1u);
    return u >> 16;
}

// Block-wide exclusive scan, 512 threads (8 waves). 2 barriers.
static __device__ __forceinline__ int block_excl_scan512(int v, int t, int* wsum8) {
    int lane = t & 63, wv = t >> 6;
    int s = v;
    #pragma unroll
    for (int off = 1; off < 64; off <<= 1) {
        int u = __shfl_up(s, off);
        if (lane >= off) s += u;
    }
    if (lane == 63) wsum8[wv] = s;
    __syncthreads();
    int add = 0;
    #pragma unroll
    for (int w = 0; w < 8; ++w) add += (w < wv) ? wsum8[w] : 0;
    __syncthreads();
    return s + add - v;      // exclusive
}

// Block-wide exclusive scan, 256 threads (4 waves). 2 barriers.
static __device__ __forceinline__ int block_excl_scan256(int v, int t, int* wsum4) {
    int lane = t & 63, wv = t >> 6;
    int s = v;
    #pragma unroll
    for (int off = 1; off < 64; off <<= 1) {
        int u = __shfl_up(s, off);
        if (lane >= off) s += u;
    }
    if (lane == 63) wsum4[wv] = s;
    __syncthreads();
    int add = 0;
    #pragma unroll
    for (int w = 0; w < 4; ++w) add += (w < wv) ? wsum4[w] : 0;
    __syncthreads();
    return s + add - v;      // exclusive
}

// ---------------------------------------------------------------------------
// K1 (512-thread blocks; partition blocks [0,NWGA) dispatch first and fill
// every CU with 4 co-resident blocks = 100% thread occupancy; norm blocks
// drain behind them):
//  partition: wg-local counting sort of <=1563 edges by bucket in LDS; sorted
//             records streamed out COALESCED into the wg's private pairs
//             slab; packed descriptor row descG[wg][b] = (runoff<<16|runlen).
//             No global atomics.
//  norm:      float4: 32 lanes/row, 16 rows/block: xn_bf = bf16(x*rsqrt(ss)),
//             norm = ||x||. Softmax later shifts by the constant |beta|
//             (exact by shift-invariance; the self-loop keeps every
//             denominator >= exp(-2|beta|) > 0).
// ---------------------------------------------------------------------------
__global__ __launch_bounds__(512)
void k_norm_part(const float* __restrict__ x,
                 const int* __restrict__ ei,
                 unsigned int* __restrict__ xn_bf,
                 float* __restrict__ norm,
                 unsigned int* __restrict__ descG,
                 unsigned int* __restrict__ pairs) {
    __shared__ int wsum8[8];
    __shared__ int cntL[NB];
    __shared__ int offL[NB];
    __shared__ unsigned int stg[CHKA];
    int t = threadIdx.x;
    if (blockIdx.x >= NWGA) {
        int nbid = blockIdx.x - NWGA;
        int l32 = t & 31;
        int node = nbid * 16 + ((t >> 6) << 1) + ((t & 63) >> 5);
        float4 v = ((const float4*)(x + (size_t)node * DF))[l32];
        float ss = v.x * v.x + v.y * v.y + v.z * v.z + v.w * v.w;
        #pragma unroll
        for (int m = 1; m < 32; m <<= 1) ss += __shfl_xor(ss, m);  // 32-lane half
        float rinv = rsqrtf(fmaxf(ss, 1e-24f));
        uint2 p;
        p.x = (f2bf(v.y * rinv) << 16) | f2bf(v.x * rinv);
        p.y = (f2bf(v.w * rinv) << 16) | f2bf(v.z * rinv);
        ((uint2*)(xn_bf + (size_t)node * 64))[l32] = p;
        if (l32 == 0) norm[node] = ss * rinv;        // == ||x||, smooth at 0
        return;
    }
    int wg = blockIdx.x;
    int e0 = wg * CHKA;
    int ec = NE - e0; if (ec > CHKA) ec = CHKA;      // last wg is short
    const int* srcp = ei + e0;
    const int* dstp = ei + NE + e0;
    for (int i = t; i < NB; i += 512) cntL[i] = 0;
    __syncthreads();
    #pragma unroll 2
    for (int i = t; i < ec; i += 512) atomicAdd(&cntL[dstp[i] / BSZ], 1);
    __syncthreads();
    {   // exclusive scan of cntL[0..NB): 3 consecutive values per thread
        int base = t * 3;
        int loc[3];
        int s = 0;
        #pragma unroll
        for (int q = 0; q < 3; ++q) {
            int idx = base + q;
            int v = (idx < NB) ? cntL[idx] : 0;
            loc[q] = s;
            s += v;
        }
        int ex = block_excl_scan512(s, t, wsum8);
        #pragma unroll
        for (int q = 0; q < 3; ++q) {
            int idx = base + q;
            if (idx < NB) offL[idx] = ex + loc[q];
        }
    }
    __syncthreads();
    // packed descriptor row, coalesced (off,cnt <= 1563 both fit 16 bits)
    for (int i = t; i < NB; i += 512)
        descG[(size_t)wg * NB + i] = ((unsigned int)offL[i] << 16) | (unsigned int)cntL[i];
    __syncthreads();                 // all offL reads done before cursor bumps
    #pragma unroll 2
    for (int i = t; i < ec; i += 512) {
        int src = srcp[i];
        int dst = dstp[i];
        int b = dst / BSZ;
        int pos = atomicAdd(&offL[b], 1);
        stg[pos] = ((unsigned int)(dst - b * BSZ) << 16) | (unsigned int)src;
    }
    __syncthreads();
    unsigned int* chunk = pairs + (size_t)wg * CHKA;
    #pragma unroll 2
    for (int i = t; i < ec; i += 512) chunk[i] = stg[i];
}

// ---------------------------------------------------------------------------
// K2 (fused build + gather): one block (256 thr) per bucket (~21.8 KB LDS ->
// 7 blocks/CU).
//  Merge: 4 descriptor scan passes (1024 runs); cooperative 4-lane run copies
//  (matched to avg run length 1.25) into rawL. Build: LDS hist over 40 local
//  dst, single-wave scan -> rp, LDS fill of colL packing bf16(norm[src]).
//  Gather: wave w handles local nodes w, w+4,...; 4 groups x 16 lanes, 2-edge
//  software pipeline; col reads are LDS.
// ---------------------------------------------------------------------------
__global__ __launch_bounds__(256)
void k_build_gather(const unsigned int* __restrict__ xn_bf,
                    const float* __restrict__ norm,
                    const unsigned int* __restrict__ descG,
                    const unsigned int* __restrict__ pairs,
                    const float* __restrict__ beta_p,
                    float* __restrict__ out) {
    __shared__ int wsum4[4];
    __shared__ unsigned short lenS[NWGA], offS[NWGA];
    __shared__ int rbase[NWGA];
    __shared__ unsigned int rawL[CAP];
    __shared__ unsigned int colL[CAP];
    __shared__ int hist[BSZ];
    __shared__ int rp[BSZ + 1];
    __shared__ int stot;
    int b = blockIdx.x, t = threadIdx.x;

    // 4 scan passes over the 1024 run descriptors (block-uniform carry)
    int runtot = 0;
    #pragma unroll
    for (int p = 0; p < 4; ++p) {
        int r = p * 256 + t;
        unsigned int d = descG[(size_t)r * NB + b];
        int len = (int)(d & 0xFFFFu);
        int ex = block_excl_scan256(len, t, wsum4);
        lenS[r] = (unsigned short)len;
        offS[r] = (unsigned short)(d >> 16);
        rbase[r] = runtot + ex;
        if (t == 255) stot = runtot + ex + len;
        __syncthreads();
        runtot = stot;
    }
    if (t < BSZ) hist[t] = 0;
    __syncthreads();
    int cnt = runtot;
    if (cnt > CAP) cnt = CAP;        // never fires (memory safety)

    // cooperative run copy: 64 groups x 4 lanes; 16 run-iterations total
    int g4 = t >> 2, l4 = t & 3;
    for (int r = g4; r < NWGA; r += 64) {
        int len = lenS[r];
        int rb = rbase[r];
        const unsigned int* sp = pairs + (size_t)r * CHKA + offS[r];
        for (int q = l4; q < len; q += 4) {
            int pos = rb + q;
            if (pos < CAP) rawL[pos] = sp[q];
        }
    }
    __syncthreads();
    for (int i = t; i < cnt; i += 256) atomicAdd(&hist[rawL[i] >> 16], 1);
    __syncthreads();
    if (t < 64) {                    // single-wave scan (BSZ=40 < 64)
        int v = (t < BSZ) ? hist[t] : 0;
        int s = v;
        #pragma unroll
        for (int off = 1; off < 64; off <<= 1) {
            int u = __shfl_up(s, off);
            if (t >= off) s += u;
        }
        if (t < BSZ) { rp[t + 1] = s; hist[t] = s - v; }   // cursor = exclusive
        if (t == 0) rp[0] = 0;
    }
    __syncthreads();
    for (int i = t; i < cnt; i += 256) {
        unsigned int p = rawL[i];
        unsigned int src = p & 0xFFFFu;
        int pos = atomicAdd(&hist[p >> 16], 1);
        colL[pos] = (f2bf(norm[src]) << 16) | src;
    }
    __syncthreads();

    // ---- gather (col/rp from LDS) ----
    int lane = t & 63;
    int w = t >> 6;
    int j = lane & 15;
    int g = lane >> 4;
    float beta = beta_p[0];
    float c = -fabsf(beta);
    for (int ln = w; ln < BSZ; ln += 4) {
        int node = b * BSZ + ln;
        uint4 du = ((const uint4*)(xn_bf + (size_t)node * 64))[j];
        float xd[8];
        #pragma unroll
        for (int q = 0; q < 4; ++q) {
            unsigned int u = (&du.x)[q];
            xd[2 * q]     = bflo(u);
            xd[2 * q + 1] = bfhi(u);
        }
        float acc[8] = {0.f, 0.f, 0.f, 0.f, 0.f, 0.f, 0.f, 0.f};
        float ssum = 0.f;
        int b0 = rp[ln], b1 = rp[ln + 1];

        int k = b0 + g;
        int kA = (k     < b1) ? k     : 0;
        int kB = (k + 4 < b1) ? k + 4 : 0;
        unsigned int pA = colL[kA];
        unsigned int pB = colL[kB];
        uint4 rA = ((const uint4*)(xn_bf + (size_t)(pA & 0xFFFFu) * 64))[j];
        uint4 rB = ((const uint4*)(xn_bf + (size_t)(pB & 0xFFFFu) * 64))[j];

        for (; k < b1; k += 8) {
            int kC = (k +  8 < b1) ? k +  8 : 0;
            int kD = (k + 12 < b1) ? k + 12 : 0;
            unsigned int pC = colL[kC];
            unsigned int pD = colL[kD];
            uint4 rC = ((const uint4*)(xn_bf + (size_t)(pC & 0xFFFFu) * 64))[j];
            uint4 rD = ((const uint4*)(xn_bf + (size_t)(pD & 0xFFFFu) * 64))[j];
            {   // edge A (always valid: k < b1)
                float xs[8];
                #pragma unroll
                for (int q = 0; q < 4; ++q) {
                    unsigned int u = (&rA.x)[q];
                    xs[2 * q]     = bflo(u);
                    xs[2 * q + 1] = bfhi(u);
                }
                float dot = 0.f;
                #pragma unroll
                for (int q = 0; q < 8; ++q) dot = fmaf(xd[q], xs[q], dot);
                dot += __shfl_xor(dot, 1);
                dot += __shfl_xor(dot, 2);
                dot += __shfl_xor(dot, 4);
                dot += __shfl_xor(dot, 8);
                float e = __expf(fmaf(beta, dot, c));
                ssum += e;
                float wgt = e * bfhi(pA);
                #pragma unroll
                for (int q = 0; q < 8; ++q) acc[q] = fmaf(wgt, xs[q], acc[q]);
            }
            {   // edge B (valid iff k+4 < b1)
                float xs[8];
                #pragma unroll
                for (int q = 0; q < 4; ++q) {
                    unsigned int u = (&rB.x)[q];
                    xs[2 * q]     = bflo(u);
                    xs[2 * q + 1] = bfhi(u);
                }
                float dot = 0.f;
                #pragma unroll
                for (int q = 0; q < 8; ++q) dot = fmaf(xd[q], xs[q], dot);
                dot += __shfl_xor(dot, 1);
                dot += __shfl_xor(dot, 2);
                dot += __shfl_xor(dot, 4);
                dot += __shfl_xor(dot, 8);
                float e = __expf(fmaf(beta, dot, c));
                e = (k + 4 < b1) ? e : 0.f;
                ssum += e;
                float wgt = e * bfhi(pB);
                #pragma unroll
                for (int q = 0; q < 8; ++q) acc[q] = fmaf(wgt, xs[q], acc[q]);
            }
            pA = pC; pB = pD; rA = rC; rB = rD;
        }

        ssum += __shfl_xor(ssum, 16);
        ssum += __shfl_xor(ssum, 32);
        #pragma unroll
        for (int q = 0; q < 8; ++q) {
            acc[q] += __shfl_xor(acc[q], 16);
            acc[q] += __shfl_xor(acc[q], 32);
        }
        float e_self = __expf(beta + c);          // self-loop, cos = 1
        ssum += e_self;
        float wsl = e_self * norm[node];
        #pragma unroll
        for (int q = 0; q < 8; ++q) acc[q] = fmaf(wsl, xd[q], acc[q]);

        if (g == 0) {
            float inv = 1.0f / ssum;
            float4 o0, o1;
            o0.x = fmaxf(0.f, acc[0] * inv); o0.y = fmaxf(0.f, acc[1] * inv);
            o0.z = fmaxf(0.f, acc[2] * inv); o0.w = fmaxf(0.f, acc[3] * inv);
            o1.x = fmaxf(0.f, acc[4] * inv); o1.y = fmaxf(0.f, acc[5] * inv);
            o1.z = fmaxf(0.f, acc[6] * inv); o1.w = fmaxf(0.f, acc[7] * inv);
            float4* op = (float4*)(out + (size_t)node * DF + 8 * j);
            op[0] = o0;
            op[1] = o1;
        }
    }
}

extern "C" void kernel_launch(void* const* d_in, const int* in_sizes, int n_in,
                              void* d_out, int out_size, void* d_ws, size_t ws_size,
                              hipStream_t stream) {
    const float* x    = (const float*)d_in[0];   // fp32 [NN*DF]
    const float* beta = (const float*)d_in[1];   // fp32 [1]
    const int*   ei   = (const int*)d_in[2];     // int32 [2*NE]
    float*       out  = (float*)d_out;           // fp32 [NN*DF]

    // workspace layout (bytes), total ~23.4 MiB:
    char* ws = (char*)d_ws;
    unsigned int* xn_bf = (unsigned int*)ws;                  // NN*64*4 = 12,800,000
    float* norm = (float*)(ws + 12800000);                    // NN*4    =    200,000
    unsigned int* descG = (unsigned int*)(ws + 13000000);     // NWGA*NB*4 = 5,120,000
    unsigned int* pairs = (unsigned int*)(ws + 18120000);     // NWGA*CHKA*4 = 6,402,048

    k_norm_part  <<<NWGA + NBF, 512, 0, stream>>>(x, ei, xn_bf, norm, descG, pairs);
    k_build_gather<<<NB,        256, 0, stream>>>(xn_bf, norm, descG, pairs, beta, out);
}